// Round 4
// baseline (9610.645 us; speedup 1.0000x reference)
//
#include <hip/hip_runtime.h>
#include <stdint.h>

typedef unsigned int u32;
typedef unsigned long long u64;
typedef long long i64;

#define NCLS 81
#define KTOP 1000
#define DETS 100
#define CANDCAP 4096
#define BIGCAP 131072
#define NBINS 65536
#define ROWTILE 16
#define TPB 128

// ---------------------------------------------------------------------------
// Fast inline f64 exp: |x| <= ~40, rel err ~1e-15 (degree-12 Taylor + 2-part
// ln2 reduction). Avoids ocml lib-call + scratch.
// ---------------------------------------------------------------------------
__device__ __forceinline__ double fast_exp(double x)
{
    const double LOG2E = 1.4426950408889634074;
    const double LN2HI = 6.93147180369123816490e-01;
    const double LN2LO = 1.90821492927058770002e-10;
    double nf = rint(x * LOG2E);
    int n = (int)nf;
    double r = fma(-nf, LN2HI, x);
    r = fma(-nf, LN2LO, r);
    double p = 2.0876756987868099e-09;          // 1/12!
    p = fma(p, r, 2.5052108385441720e-08);      // 1/11!
    p = fma(p, r, 2.7557319223985891e-07);      // 1/10!
    p = fma(p, r, 2.7557319223985893e-06);      // 1/9!
    p = fma(p, r, 2.4801587301587302e-05);      // 1/8!
    p = fma(p, r, 1.9841269841269841e-04);      // 1/7!
    p = fma(p, r, 1.3888888888888889e-03);      // 1/6!
    p = fma(p, r, 8.3333333333333332e-03);      // 1/5!
    p = fma(p, r, 4.1666666666666664e-02);      // 1/4!
    p = fma(p, r, 1.6666666666666666e-01);      // 1/3!
    p = fma(p, r, 5.0000000000000000e-01);      // 1/2!
    p = fma(p, r, 1.0);
    p = fma(p, r, 1.0);
    i64 bits = ((i64)(n + 1023)) << 52;         // 2^n (n in [-40, 3] here)
    return p * __longlong_as_double(bits);
}

// ---------------------------------------------------------------------------
// Softmax + filter + emit. Rows staged in LDS (no scratch, runtime class idx
// is a ds_read). f64 selection semantics identical to round-2 (absmax 0.0).
// MODE 0: histogram only (two-pass path, pass 1)
// MODE 1: compact candidates with key >= floorKey (two-pass path, pass 2)
// MODE 2: histogram + compact ALL candidates (fused path, single logits read)
// ---------------------------------------------------------------------------
template<int MODE>
__global__ __launch_bounds__(TPB)
void score_kernel(const float* __restrict__ logits, const float* __restrict__ rel,
                  const float* __restrict__ priors, const float* __restrict__ ts,
                  int P, u32* __restrict__ hist, const u32* __restrict__ floorKey,
                  u64* __restrict__ outBuf, u32* __restrict__ outCnt, int cap)
{
    __shared__ float xs[TPB * NCLS];      // 41.5 KB: 128 priors x 81 classes
    int img = blockIdx.y;
    int p0 = blockIdx.x * TPB;
    int tid = threadIdx.x;
    int lane = tid & 63;
    int nrows = min(TPB, P - p0);
    int nflat = nrows * NCLS;
    const float* src = logits + ((size_t)img * P + p0) * NCLS;

    if (nflat == TPB * NCLS) {
        // full tile: coalesced float4 (tile base is 16B-aligned: 128*81*4 % 16 == 0)
        const float4* s4 = (const float4*)src;
        float4* d4 = (float4*)xs;
#pragma unroll
        for (int k = 0; k < 20; ++k)                   // 20*128 = 2560 float4
            d4[k * TPB + tid] = s4[k * TPB + tid];
        xs[10240 + tid] = src[10240 + tid];            // 128-float tail
    } else {
        for (int k = tid; k < nflat; k += TPB) xs[k] = src[k];
    }
    __syncthreads();

    int p = p0 + tid;
    const float* row = xs + tid * NCLS;
    bool ok = false;
    float mf = 0.0f, tf_lo = 0.0f;
    double md = 0.0, s = 0.0;
    if (p < P) {
        float m = row[0];
        for (int c = 1; c < NCLS; ++c) m = fmaxf(m, row[c]);  // exact, matches np
        mf = m; md = (double)m;
        double acc = 0.0;
        for (int c = 0; c < NCLS; ++c)
            acc += fast_exp((double)row[c] - md);             // f64 softmax denom
        s = acc;
        tf_lo = logf(0.05f * (float)s) - 3e-4f;               // conservative prefilter

        // f64 size filter (margin is huge; keep truth-level anyway)
        const float* rp = rel + ((size_t)img * P + p) * 4;
        const float* pp = priors + (size_t)p * 4;
        double pw = pp[2], ph = pp[3];
        double cx = (double)pp[0] + (double)rp[0] * 0.1 * pw;
        double cy = (double)pp[1] + (double)rp[1] * 0.1 * ph;
        double bw = pw * fast_exp((double)rp[2] * 0.2);
        double bh = ph * fast_exp((double)rp[3] * 0.2);
        double sw = (double)ts[img * 2 + 1], sh = (double)ts[img * 2 + 0];
        double x1 = (cx - bw * 0.5) * sw, x2 = (cx + bw * 0.5) * sw;
        double y1 = (cy - bh * 0.5) * sh, y2 = (cy + bh * 0.5) * sh;
        ok = (x2 - x1 >= 0.01) && (y2 - y1 >= 0.01);
    }

    u32 fkey = (MODE == 1) ? floorKey[img] : 0u;
    for (int c = 1; c < NCLS; ++c) {
        bool emit = false;
        u32 key = 0;
        if (ok) {
            float df = row[c] - mf;
            if (df > tf_lo) {                          // rare (~2.3/prior)
                double e = fast_exp((double)row[c] - md);
                double sc = e / s;                     // exact reference semantics
                if (sc > 0.05) {
                    key = __float_as_uint((float)sc) ^ 0x80000000u;
                    emit = true;
                }
            }
        }
        if (MODE == 0) {
            if (emit) atomicAdd(&hist[(size_t)img * NBINS + (key >> 16)], 1u);
        } else {
            if (MODE == 2 && emit) atomicAdd(&hist[(size_t)img * NBINS + (key >> 16)], 1u);
            bool em2 = emit && (MODE == 2 || key >= fkey);
            u64 mask = __ballot(em2);
            if (mask) {       // wave-aggregated compaction: 1 atomic per wave per class
                int leader = __ffsll((long long)mask) - 1;
                u32 nact = (u32)__popcll(mask);
                u32 basePos = 0;
                if (lane == leader) basePos = atomicAdd(&outCnt[img], nact);
                basePos = __shfl(basePos, leader);
                if (em2) {
                    u32 rank = (u32)__popcll(mask & ((1ULL << lane) - 1ULL));
                    u32 pos = basePos + rank;
                    if ((int)pos < cap) {
                        u32 idx = (u32)p * 80u + (u32)(c - 1);   // flat idx in [P,80]
                        // sort key: (score desc, idx asc) == u64 desc
                        outBuf[(size_t)img * cap + pos] = ((u64)key << 32) | (u64)(u32)(~idx);
                    }
                }
            }
        }
    }
}

// Find minimal 16-bit bin F with suffix count >= KTOP; floorKey = F<<16.
__global__ __launch_bounds__(256)
void select_floor_kernel(const u32* __restrict__ hist, u32* __restrict__ floorKey)
{
    int img = blockIdx.x;
    int t = threadIdx.x;
    __shared__ u32 csum[256];
    __shared__ u32 hbin[256];
    __shared__ int s_c;
    __shared__ u32 s_run;
    const u32* h = hist + (size_t)img * NBINS;
    u32 acc = 0;
    for (int b = 0; b < 256; ++b) acc += h[t * 256 + b];
    csum[t] = acc;
    __syncthreads();
    if (t == 0) {
        u32 run = 0; int c = 255;
        for (; c >= 0; --c) {
            if (run + csum[c] >= KTOP) break;
            run += csum[c];
        }
        s_c = c; s_run = run;
    }
    __syncthreads();
    int c = s_c;
    if (c < 0) { if (t == 0) floorKey[img] = 0u; return; }
    hbin[t] = h[c * 256 + t];
    __syncthreads();
    if (t == 0) {
        u32 run = s_run;
        int b = 255;
        for (; b >= 0; --b) {
            run += hbin[b];
            if (run >= KTOP) break;
        }
        floorKey[img] = ((u32)(c * 256 + b)) << 16;
    }
}

// Fused path pass 2: filter big candidate list down to key >= floorKey.
__global__ __launch_bounds__(256)
void compact_kernel(const u64* __restrict__ big, const u32* __restrict__ bigCnt,
                    const u32* __restrict__ floorKey,
                    u64* __restrict__ cand, u32* __restrict__ candCnt)
{
    int img = blockIdx.y;
    u32 bc = bigCnt[img]; if (bc > (u32)BIGCAP) bc = BIGCAP;
    u32 k = blockIdx.x * 256 + threadIdx.x;
    if (k >= bc) return;
    u64 e = big[(size_t)img * BIGCAP + k];
    if ((u32)(e >> 32) >= floorKey[img]) {
        u32 pos = atomicAdd(&candCnt[img], 1u);
        if (pos < CANDCAP) cand[(size_t)img * CANDCAP + pos] = e;
    }
}

// Bitonic-sort candidates (desc), take top-1000, f64-decode their boxes,
// store f64 (for IoU) + f32 (for output), reduce maxc in f64.
__global__ __launch_bounds__(1024)
void sort_select_kernel(const u64* __restrict__ cand, const u32* __restrict__ candCnt,
                        const float* __restrict__ rel, const float* __restrict__ priors,
                        const float* __restrict__ ts, int P,
                        double* __restrict__ selBoxD, float* __restrict__ selBox,
                        float* __restrict__ selSc, int* __restrict__ selCl,
                        double* __restrict__ maxcArr)
{
    int img = blockIdx.x;
    int tid = threadIdx.x;
    __shared__ u64 s[CANDCAP];
    u32 n = candCnt[img]; if (n > CANDCAP) n = CANDCAP;
    for (int k = tid; k < CANDCAP; k += 1024)
        s[k] = (k < (int)n) ? cand[(size_t)img * CANDCAP + k] : 0ULL;
    __syncthreads();
    for (u32 len = 2; len <= CANDCAP; len <<= 1) {
        for (u32 j = len >> 1; j > 0; j >>= 1) {
            for (int i = tid; i < CANDCAP; i += 1024) {
                u32 ixj = (u32)i ^ j;
                if (ixj > (u32)i) {
                    u64 a = s[i], b = s[ixj];
                    bool up = ((i & len) == 0);          // descending overall
                    if (up ? (a < b) : (a > b)) { s[i] = b; s[ixj] = a; }
                }
            }
            __syncthreads();
        }
    }
    double v = -1e300;
    if (tid < KTOP) {
        u64 e = s[tid];
        float score = -1.0f; int cls = 0;
        double b0 = 0, b1 = 0, b2 = 0, b3 = 0;
        if ((e >> 32) != 0ULL) {
            u32 key = (u32)(e >> 32);
            score = __uint_as_float(key ^ 0x80000000u);
            u32 idx = ~((u32)e);
            int p = (int)(idx / 80u), c0 = (int)(idx % 80u);
            cls = c0;
            const float* rp = rel + ((size_t)img * P + p) * 4;
            const float* pp = priors + (size_t)p * 4;
            double pw = pp[2], ph = pp[3];
            double cx = (double)pp[0] + (double)rp[0] * 0.1 * pw;
            double cy = (double)pp[1] + (double)rp[1] * 0.1 * ph;
            double bw = pw * fast_exp((double)rp[2] * 0.2);
            double bh = ph * fast_exp((double)rp[3] * 0.2);
            double sw = (double)ts[img * 2 + 1], sh = (double)ts[img * 2 + 0];
            b0 = (cx - bw * 0.5) * sw; b1 = (cy - bh * 0.5) * sh;
            b2 = (cx + bw * 0.5) * sw; b3 = (cy + bh * 0.5) * sh;
            v = fmax(fmax(b0, b1), fmax(b2, b3));   // valid -> box coords
        } else {
            v = 0.0;                                // invalid -> 0 (where(valid,b,0))
        }
        size_t o = (size_t)img * 1024 + tid;
        selSc[o] = score; selCl[o] = cls;
        selBoxD[o * 4 + 0] = b0; selBoxD[o * 4 + 1] = b1;
        selBoxD[o * 4 + 2] = b2; selBoxD[o * 4 + 3] = b3;
        ((float4*)selBox)[o] = make_float4((float)b0, (float)b1, (float)b2, (float)b3);
    }
    __shared__ double red[1024];
    red[tid] = v;
    __syncthreads();
    for (int off = 512; off > 0; off >>= 1) {
        if (tid < off) red[tid] = fmax(red[tid], red[tid + off]);
        __syncthreads();
    }
    if (tid == 0) maxcArr[img] = red[0];
}

// 16 rows per block, 1000 boxes staged in LDS; f64 IoU on class-offset boxes
// -> 16-word bitmask row per i.
__global__ __launch_bounds__(256)
void iou_kernel(const double* __restrict__ selBoxD, const int* __restrict__ selCl,
                const double* __restrict__ maxcArr, u64* __restrict__ iouMask)
{
    int img = blockIdx.y;
    int i0 = blockIdx.x * ROWTILE;
    int tid = threadIdx.x, wave = tid >> 6, lane = tid & 63;
    __shared__ double sb[KTOP][5];   // pad stride 40B
    __shared__ int scls[KTOP];
    size_t base = (size_t)img * 1024;
    for (int j = tid; j < KTOP; j += 256) {
        sb[j][0] = selBoxD[(base + j) * 4 + 0];
        sb[j][1] = selBoxD[(base + j) * 4 + 1];
        sb[j][2] = selBoxD[(base + j) * 4 + 2];
        sb[j][3] = selBoxD[(base + j) * 4 + 3];
        scls[j] = selCl[base + j];
    }
    __syncthreads();
    double maxc1 = maxcArr[img] + 1.0;
    for (int r = 0; r < 4; ++r) {
        int i = i0 + wave * 4 + r;           // uniform across the wave
        if (i >= KTOP) continue;
        double offA = (double)scls[i] * maxc1;
        double a0 = sb[i][0] + offA, a1 = sb[i][1] + offA;
        double a2 = sb[i][2] + offA, a3 = sb[i][3] + offA;
        double areaA = (a2 - a0) * (a3 - a1);
        for (int ch = 0; ch < 16; ++ch) {
            int j = ch * 64 + lane;
            bool pred = false;
            if (j < KTOP) {
                double offB = (double)scls[j] * maxc1;
                double b0 = sb[j][0] + offB, b1 = sb[j][1] + offB;
                double b2 = sb[j][2] + offB, b3 = sb[j][3] + offB;
                double areaB = (b2 - b0) * (b3 - b1);
                double ltx = fmax(a0, b0), lty = fmax(a1, b1);
                double rbx = fmin(a2, b2), rby = fmin(a3, b3);
                double wx = fmax(rbx - ltx, 0.0), wy = fmax(rby - lty, 0.0);
                double inter = wx * wy;
                double iou = inter / (((areaA + areaB) - inter) + 1e-12);
                pred = iou > 0.45;
            }
            u64 bal = __ballot(pred);
            if (lane == 0) iouMask[((size_t)img * KTOP + i) * 16 + ch] = bal;
        }
    }
}

// Single-wave sequential greedy NMS + final top-100 write-out.
__global__ __launch_bounds__(64)
void nms_out_kernel(const float* __restrict__ selBox, const float* __restrict__ selSc,
                    const int* __restrict__ selCl, const u64* __restrict__ iouMask,
                    float* __restrict__ out, int B)
{
    int img = blockIdx.x;
    int lane = threadIdx.x;
    size_t base = (size_t)img * 1024;
    u64 validW = 0, removed = 0;   // lane w (<16) owns bitset word w
#pragma unroll
    for (int w = 0; w < 16; ++w) {
        int j = w * 64 + lane;
        bool v = (j < KTOP) ? (selSc[base + j] > 0.05f) : false;
        u64 mk = __ballot(v);
        if (lane == w) validW = mk;
    }
    __shared__ int keptIdx[DETS];
    int cnt = 0;
    const u64* rows = iouMask + (size_t)img * KTOP * 16;
    for (int i = 0; i < KTOP; ++i) {
        int w0 = i >> 6, b0 = i & 63;
        u64 rw = __shfl(removed, w0);
        u64 vw = __shfl(validW, w0);
        bool sup = (rw >> b0) & 1ULL;
        bool val = (vw >> b0) & 1ULL;
        if (val && !sup) {
            if (lane < 16) removed |= rows[(size_t)i * 16 + lane];
            if (lane == 0) keptIdx[cnt] = i;
            cnt++;
            if (cnt == DETS) break;
        }
    }
    __syncthreads();
    for (int r = lane; r < DETS; r += 64) {
        float b0 = 0.f, b1 = 0.f, b2 = 0.f, b3 = 0.f, sc = 0.f, lb = -1.0f, vd = 0.f;
        if (r < cnt) {
            int i = keptIdx[r];
            float4 bb = ((const float4*)selBox)[base + i];
            b0 = bb.x; b1 = bb.y; b2 = bb.z; b3 = bb.w;
            sc = selSc[base + i];
            lb = (float)(selCl[base + i] + 1);
            vd = 1.0f;
        }
        ((float4*)out)[(size_t)img * DETS + r] = make_float4(b0, b1, b2, b3);
        out[(size_t)B * 400 + (size_t)img * DETS + r] = sc;   // scores
        out[(size_t)B * 500 + (size_t)img * DETS + r] = lb;   // labels (as f32)
        out[(size_t)B * 600 + (size_t)img * DETS + r] = vd;   // valid (as f32)
    }
}

extern "C" void kernel_launch(void* const* d_in, const int* in_sizes, int n_in,
                              void* d_out, int out_size, void* d_ws, size_t ws_size,
                              hipStream_t stream)
{
    const float* logits = (const float*)d_in[0];
    const float* rel    = (const float*)d_in[1];
    const float* priors = (const float*)d_in[2];
    const float* ts     = (const float*)d_in[3];
    float* out = (float*)d_out;
    int P = in_sizes[2] / 4;
    int B = in_sizes[3] / 2;

    char* ws = (char*)d_ws;
    size_t o_hist    = 0;
    size_t o_cnt     = o_hist + (size_t)B * NBINS * 4;
    size_t o_bigcnt  = o_cnt + (size_t)B * 4;
    size_t o_floor   = o_bigcnt + (size_t)B * 4;
    size_t zero_bytes = o_floor;                       // hist + candCnt + bigCnt
    size_t o_cand    = (o_floor + (size_t)B * 4 + 255) & ~(size_t)255;
    size_t o_selboxD = o_cand + (size_t)B * CANDCAP * 8;
    size_t o_selbox  = o_selboxD + (size_t)B * 1024 * 32;
    size_t o_selsc   = o_selbox + (size_t)B * 1024 * 16;
    size_t o_selcl   = o_selsc + (size_t)B * 1024 * 4;
    size_t o_maxc    = o_selcl + (size_t)B * 1024 * 4;
    size_t o_iou     = (o_maxc + (size_t)B * 8 + 255) & ~(size_t)255;
    size_t o_big     = o_iou + (size_t)B * KTOP * 16 * 8;
    size_t need_fused = o_big + (size_t)B * BIGCAP * 8;

    u32* hist      = (u32*)(ws + o_hist);
    u32* candCnt   = (u32*)(ws + o_cnt);
    u32* bigCnt    = (u32*)(ws + o_bigcnt);
    u32* floorKey  = (u32*)(ws + o_floor);
    u64* cand      = (u64*)(ws + o_cand);
    double* selBoxD = (double*)(ws + o_selboxD);
    float* selBox  = (float*)(ws + o_selbox);
    float* selSc   = (float*)(ws + o_selsc);
    int*   selCl   = (int*)(ws + o_selcl);
    double* maxc   = (double*)(ws + o_maxc);
    u64* iouMask   = (u64*)(ws + o_iou);
    u64* bigCand   = (u64*)(ws + o_big);

    bool fused = (ws_size >= need_fused);

    hipMemsetAsync(ws, 0, zero_bytes, stream);

    dim3 g1((P + TPB - 1) / TPB, B);
    if (fused) {
        // single logits read: candidates + histogram in one pass
        score_kernel<2><<<g1, TPB, 0, stream>>>(logits, rel, priors, ts, P,
                                                hist, nullptr, bigCand, bigCnt, BIGCAP);
        select_floor_kernel<<<B, 256, 0, stream>>>(hist, floorKey);
        compact_kernel<<<dim3(BIGCAP / 256, B), 256, 0, stream>>>(bigCand, bigCnt, floorKey,
                                                                  cand, candCnt);
    } else {
        // safe low-workspace path: logits read twice
        score_kernel<0><<<g1, TPB, 0, stream>>>(logits, rel, priors, ts, P,
                                                hist, nullptr, nullptr, nullptr, 0);
        select_floor_kernel<<<B, 256, 0, stream>>>(hist, floorKey);
        score_kernel<1><<<g1, TPB, 0, stream>>>(logits, rel, priors, ts, P,
                                                hist, floorKey, cand, candCnt, CANDCAP);
    }
    sort_select_kernel<<<B, 1024, 0, stream>>>(cand, candCnt, rel, priors, ts, P,
                                               selBoxD, selBox, selSc, selCl, maxc);
    iou_kernel<<<dim3((KTOP + ROWTILE - 1) / ROWTILE, B), 256, 0, stream>>>(
        selBoxD, selCl, maxc, iouMask);
    nms_out_kernel<<<B, 64, 0, stream>>>(selBox, selSc, selCl, iouMask, out, B);
    (void)n_in; (void)out_size;
}

// Round 7
// 603.901 us; speedup vs baseline: 15.9143x; 15.9143x over previous
//
#include <hip/hip_runtime.h>
#include <stdint.h>

typedef unsigned int u32;
typedef unsigned long long u64;
typedef long long i64;

#define NCLS 81
#define KTOP 1000
#define DETS 100
#define CANDCAP 4096
#define BIGCAP 131072
#define ROWTILE 16
#define TPB 128
#define CNT_STRIDE 32     // pad per-image counters to 128 B (atomic line isolation)
#define FBINS 4096

// ---------------------------------------------------------------------------
// Fast inline f64 exp: |x| <= ~40, rel err ~1e-15 (degree-12 Taylor + 2-part
// ln2 reduction). Avoids ocml lib-call.
// ---------------------------------------------------------------------------
__device__ __forceinline__ double fast_exp(double x)
{
    const double LOG2E = 1.4426950408889634074;
    const double LN2HI = 6.93147180369123816490e-01;
    const double LN2LO = 1.90821492927058770002e-10;
    double nf = rint(x * LOG2E);
    int n = (int)nf;
    double r = fma(-nf, LN2HI, x);
    r = fma(-nf, LN2LO, r);
    double p = 2.0876756987868099e-09;          // 1/12!
    p = fma(p, r, 2.5052108385441720e-08);
    p = fma(p, r, 2.7557319223985891e-07);
    p = fma(p, r, 2.7557319223985893e-06);
    p = fma(p, r, 2.4801587301587302e-05);
    p = fma(p, r, 1.9841269841269841e-04);
    p = fma(p, r, 1.3888888888888889e-03);
    p = fma(p, r, 8.3333333333333332e-03);
    p = fma(p, r, 4.1666666666666664e-02);
    p = fma(p, r, 1.6666666666666666e-01);
    p = fma(p, r, 5.0000000000000000e-01);
    p = fma(p, r, 1.0);
    p = fma(p, r, 1.0);
    i64 bits = ((i64)(n + 1023)) << 52;         // 2^n (n in [-40, 3] here)
    return p * __longlong_as_double(bits);
}

// ---------------------------------------------------------------------------
// One pass over logits. LDS row staging; f64 selection semantics (absmax 0.0
// proven). NO per-element global atomics: per-thread count -> block prefix
// sum -> ONE atomicAdd per block -> plain stores.
// ---------------------------------------------------------------------------
__global__ __launch_bounds__(TPB)
void score_kernel(const float* __restrict__ logits, const float* __restrict__ rel,
                  const float* __restrict__ priors, const float* __restrict__ ts,
                  int P, u64* __restrict__ bigCand, u32* __restrict__ bigCnt)
{
    __shared__ float xs[TPB * NCLS];      // 41.5 KB: 128 priors x 81 classes
    __shared__ u32 pscan[TPB];
    __shared__ u32 s_base;
    int img = blockIdx.y;
    int p0 = blockIdx.x * TPB;
    int tid = threadIdx.x;
    int nrows = min(TPB, P - p0);
    int nflat = nrows * NCLS;
    const float* src = logits + ((size_t)img * P + p0) * NCLS;

    if (nflat == TPB * NCLS) {
        // full tile: coalesced float4 (tile base 16B-aligned: 128*81*4 % 16 == 0)
        const float4* s4 = (const float4*)src;
        float4* d4 = (float4*)xs;
#pragma unroll
        for (int k = 0; k < 20; ++k)                   // 20*128 = 2560 float4
            d4[k * TPB + tid] = s4[k * TPB + tid];
        xs[10240 + tid] = src[10240 + tid];            // 128-float tail
    } else {
        for (int k = tid; k < nflat; k += TPB) xs[k] = src[k];
    }
    __syncthreads();

    int p = p0 + tid;
    const float* row = xs + tid * NCLS;
    bool ok = false;
    float mf = 0.0f, tf_lo = 0.0f;
    double md = 0.0, s = 0.0;
    if (p < P) {
        float m = row[0];
        for (int c = 1; c < NCLS; ++c) m = fmaxf(m, row[c]);  // exact, matches np
        mf = m; md = (double)m;
        double acc = 0.0;
        for (int c = 0; c < NCLS; ++c)
            acc += fast_exp((double)row[c] - md);             // f64 softmax denom
        s = acc;
        tf_lo = logf(0.05f * (float)s) - 3e-4f;               // conservative prefilter

        // f64 size filter
        const float* rp = rel + ((size_t)img * P + p) * 4;
        const float* pp = priors + (size_t)p * 4;
        double pw = pp[2], ph = pp[3];
        double cx = (double)pp[0] + (double)rp[0] * 0.1 * pw;
        double cy = (double)pp[1] + (double)rp[1] * 0.1 * ph;
        double bw = pw * fast_exp((double)rp[2] * 0.2);
        double bh = ph * fast_exp((double)rp[3] * 0.2);
        double sw = (double)ts[img * 2 + 1], sh = (double)ts[img * 2 + 0];
        double x1 = (cx - bw * 0.5) * sw, x2 = (cx + bw * 0.5) * sw;
        double y1 = (cy - bh * 0.5) * sh, y2 = (cy + bh * 0.5) * sh;
        ok = (x2 - x1 >= 0.01) && (y2 - y1 >= 0.01);
    }

    // ---- phase 1: count emits (exact f64 decision, same as emit phase) ----
    u32 cnt = 0;
    if (ok) {
        for (int c = 1; c < NCLS; ++c) {
            float df = row[c] - mf;
            if (df > tf_lo) {                          // rare (~2.3/prior)
                double e = fast_exp((double)row[c] - md);
                if (e / s > 0.05) cnt++;
            }
        }
    }
    pscan[tid] = cnt;
    __syncthreads();
    // inclusive Hillis-Steele scan over 128
    for (int off = 1; off < TPB; off <<= 1) {
        u32 v = (tid >= off) ? pscan[tid - off] : 0;
        __syncthreads();
        pscan[tid] += v;
        __syncthreads();
    }
    if (tid == TPB - 1)
        s_base = atomicAdd(&bigCnt[(size_t)img * CNT_STRIDE], pscan[tid]);  // 1 atomic/block
    __syncthreads();
    u32 base = s_base + pscan[tid] - cnt;              // exclusive prefix

    // ---- phase 2: emit (identical decisions; plain global stores) ----
    if (ok && cnt) {
        u32 w = 0;
        for (int c = 1; c < NCLS; ++c) {
            float df = row[c] - mf;
            if (df > tf_lo) {
                double e = fast_exp((double)row[c] - md);
                double sc = e / s;
                if (sc > 0.05) {
                    u32 key = __float_as_uint((float)sc) ^ 0x80000000u;
                    u32 pos = base + w++;
                    if (pos < BIGCAP) {
                        u32 idx = (u32)p * 80u + (u32)(c - 1);   // flat idx in [P,80]
                        // sort key: (score desc, idx asc) == u64 desc
                        bigCand[(size_t)img * BIGCAP + pos] = ((u64)key << 32) | (u64)(u32)(~idx);
                    }
                }
            }
        }
    }
}

// ---------------------------------------------------------------------------
// One block per image: 16-bit floor key from bigCand via two LDS-hist passes
// (4096-bin on key[31:20], then 16-bin on key[19:16]). Same semantics as the
// old global-hist floor select.
// ---------------------------------------------------------------------------
__global__ __launch_bounds__(1024)
void floor_kernel(const u64* __restrict__ bigCand, const u32* __restrict__ bigCnt,
                  u32* __restrict__ floorKey)
{
    int img = blockIdx.x;
    int tid = threadIdx.x;
    __shared__ u32 h[FBINS];
    __shared__ u32 s_sel, s_run;
    u32 bc = bigCnt[(size_t)img * CNT_STRIDE];
    if (bc > (u32)BIGCAP) bc = BIGCAP;
    const u64* src = bigCand + (size_t)img * BIGCAP;

    for (int i = tid; i < FBINS; i += 1024) h[i] = 0;
    __syncthreads();
    for (u32 k = tid; k < bc; k += 1024)
        atomicAdd(&h[(u32)(src[k] >> 32) >> 20], 1u);
    __syncthreads();
    if (tid == 0) {
        u32 run = 0; int d = FBINS - 1;
        for (; d >= 0; --d) {
            if (run + h[d] >= KTOP) break;
            run += h[d];
        }
        s_sel = (u32)d;          // 0xFFFFFFFF if d == -1 (total < KTOP)
        s_run = run;
    }
    __syncthreads();
    u32 d12 = s_sel;
    if ((int)d12 < 0) { if (tid == 0) floorKey[img] = 0u; return; }
    u32 run0 = s_run;
    if (tid < 16) h[tid] = 0;
    __syncthreads();
    for (u32 k = tid; k < bc; k += 1024) {
        u32 key = (u32)(src[k] >> 32);
        if ((key >> 20) == d12) atomicAdd(&h[(key >> 16) & 0xF], 1u);
    }
    __syncthreads();
    if (tid == 0) {
        u32 run = run0;
        int b = 15;
        for (; b >= 0; --b) {
            run += h[b];
            if (run >= KTOP) break;
        }
        if (b < 0) b = 0;
        floorKey[img] = ((d12 << 4) | (u32)b) << 16;
    }
}

// Filter big candidate list down to key >= floorKey (wave-aggregated atomic).
__global__ __launch_bounds__(256)
void compact_kernel(const u64* __restrict__ big, const u32* __restrict__ bigCnt,
                    const u32* __restrict__ floorKey,
                    u64* __restrict__ cand, u32* __restrict__ candCnt)
{
    int img = blockIdx.y;
    int lane = threadIdx.x & 63;
    u32 bc = bigCnt[(size_t)img * CNT_STRIDE]; if (bc > (u32)BIGCAP) bc = BIGCAP;
    u32 k = blockIdx.x * 256 + threadIdx.x;
    u64 e = 0; bool pass = false;
    if (k < bc) {
        e = big[(size_t)img * BIGCAP + k];
        pass = ((u32)(e >> 32) >= floorKey[img]);
    }
    u64 mask = __ballot(pass);
    if (!mask) return;
    int leader = __ffsll((long long)mask) - 1;
    u32 basePos = 0;
    if (lane == leader)
        basePos = atomicAdd(&candCnt[(size_t)img * CNT_STRIDE], (u32)__popcll(mask));
    basePos = __shfl(basePos, leader);
    if (pass) {
        u32 pos = basePos + (u32)__popcll(mask & ((1ULL << lane) - 1ULL));
        if (pos < CANDCAP) cand[(size_t)img * CANDCAP + pos] = e;
    }
}

// Bitonic-sort candidates (desc), take top-1000, f64-decode their boxes,
// store f64 (for IoU) + f32 (for output), reduce maxc in f64.
__global__ __launch_bounds__(1024)
void sort_select_kernel(const u64* __restrict__ cand, const u32* __restrict__ candCnt,
                        const float* __restrict__ rel, const float* __restrict__ priors,
                        const float* __restrict__ ts, int P,
                        double* __restrict__ selBoxD, float* __restrict__ selBox,
                        float* __restrict__ selSc, int* __restrict__ selCl,
                        double* __restrict__ maxcArr)
{
    int img = blockIdx.x;
    int tid = threadIdx.x;
    __shared__ u64 s[CANDCAP];
    u32 n = candCnt[(size_t)img * CNT_STRIDE]; if (n > CANDCAP) n = CANDCAP;
    for (int k = tid; k < CANDCAP; k += 1024)
        s[k] = (k < (int)n) ? cand[(size_t)img * CANDCAP + k] : 0ULL;
    __syncthreads();
    for (u32 len = 2; len <= CANDCAP; len <<= 1) {
        for (u32 j = len >> 1; j > 0; j >>= 1) {
            for (int i = tid; i < CANDCAP; i += 1024) {
                u32 ixj = (u32)i ^ j;
                if (ixj > (u32)i) {
                    u64 a = s[i], b = s[ixj];
                    bool up = ((i & len) == 0);          // descending overall
                    if (up ? (a < b) : (a > b)) { s[i] = b; s[ixj] = a; }
                }
            }
            __syncthreads();
        }
    }
    double v = -1e300;
    if (tid < KTOP) {
        u64 e = s[tid];
        float score = -1.0f; int cls = 0;
        double b0 = 0, b1 = 0, b2 = 0, b3 = 0;
        if ((e >> 32) != 0ULL) {
            u32 key = (u32)(e >> 32);
            score = __uint_as_float(key ^ 0x80000000u);
            u32 idx = ~((u32)e);
            int p = (int)(idx / 80u), c0 = (int)(idx % 80u);
            cls = c0;
            const float* rp = rel + ((size_t)img * P + p) * 4;
            const float* pp = priors + (size_t)p * 4;
            double pw = pp[2], ph = pp[3];
            double cx = (double)pp[0] + (double)rp[0] * 0.1 * pw;
            double cy = (double)pp[1] + (double)rp[1] * 0.1 * ph;
            double bw = pw * fast_exp((double)rp[2] * 0.2);
            double bh = ph * fast_exp((double)rp[3] * 0.2);
            double sw = (double)ts[img * 2 + 1], sh = (double)ts[img * 2 + 0];
            b0 = (cx - bw * 0.5) * sw; b1 = (cy - bh * 0.5) * sh;
            b2 = (cx + bw * 0.5) * sw; b3 = (cy + bh * 0.5) * sh;
            v = fmax(fmax(b0, b1), fmax(b2, b3));   // valid -> box coords
        } else {
            v = 0.0;                                // invalid -> 0 (where(valid,b,0))
        }
        size_t o = (size_t)img * 1024 + tid;
        selSc[o] = score; selCl[o] = cls;
        selBoxD[o * 4 + 0] = b0; selBoxD[o * 4 + 1] = b1;
        selBoxD[o * 4 + 2] = b2; selBoxD[o * 4 + 3] = b3;
        ((float4*)selBox)[o] = make_float4((float)b0, (float)b1, (float)b2, (float)b3);
    }
    __shared__ double red[1024];
    red[tid] = v;
    __syncthreads();
    for (int off = 512; off > 0; off >>= 1) {
        if (tid < off) red[tid] = fmax(red[tid], red[tid + off]);
        __syncthreads();
    }
    if (tid == 0) maxcArr[img] = red[0];
}

// 16 rows per block, 1000 boxes staged in LDS; f64 IoU on class-offset boxes
// -> 16-word bitmask row per i.
__global__ __launch_bounds__(256)
void iou_kernel(const double* __restrict__ selBoxD, const int* __restrict__ selCl,
                const double* __restrict__ maxcArr, u64* __restrict__ iouMask)
{
    int img = blockIdx.y;
    int i0 = blockIdx.x * ROWTILE;
    int tid = threadIdx.x, wave = tid >> 6, lane = tid & 63;
    __shared__ double sb[KTOP][5];   // pad stride 40B
    __shared__ int scls[KTOP];
    size_t base = (size_t)img * 1024;
    for (int j = tid; j < KTOP; j += 256) {
        sb[j][0] = selBoxD[(base + j) * 4 + 0];
        sb[j][1] = selBoxD[(base + j) * 4 + 1];
        sb[j][2] = selBoxD[(base + j) * 4 + 2];
        sb[j][3] = selBoxD[(base + j) * 4 + 3];
        scls[j] = selCl[base + j];
    }
    __syncthreads();
    double maxc1 = maxcArr[img] + 1.0;
    for (int r = 0; r < 4; ++r) {
        int i = i0 + wave * 4 + r;           // uniform across the wave
        if (i >= KTOP) continue;
        double offA = (double)scls[i] * maxc1;
        double a0 = sb[i][0] + offA, a1 = sb[i][1] + offA;
        double a2 = sb[i][2] + offA, a3 = sb[i][3] + offA;
        double areaA = (a2 - a0) * (a3 - a1);
        for (int ch = 0; ch < 16; ++ch) {
            int j = ch * 64 + lane;
            bool pred = false;
            if (j < KTOP) {
                double offB = (double)scls[j] * maxc1;
                double b0 = sb[j][0] + offB, b1 = sb[j][1] + offB;
                double b2 = sb[j][2] + offB, b3 = sb[j][3] + offB;
                double areaB = (b2 - b0) * (b3 - b1);
                double ltx = fmax(a0, b0), lty = fmax(a1, b1);
                double rbx = fmin(a2, b2), rby = fmin(a3, b3);
                double wx = fmax(rbx - ltx, 0.0), wy = fmax(rby - lty, 0.0);
                double inter = wx * wy;
                double iou = inter / (((areaA + areaB) - inter) + 1e-12);
                pred = iou > 0.45;
            }
            u64 bal = __ballot(pred);
            if (lane == 0) iouMask[((size_t)img * KTOP + i) * 16 + ch] = bal;
        }
    }
}

// Single-wave sequential greedy NMS + final top-100 write-out.
__global__ __launch_bounds__(64)
void nms_out_kernel(const float* __restrict__ selBox, const float* __restrict__ selSc,
                    const int* __restrict__ selCl, const u64* __restrict__ iouMask,
                    float* __restrict__ out, int B)
{
    int img = blockIdx.x;
    int lane = threadIdx.x;
    size_t base = (size_t)img * 1024;
    u64 validW = 0, removed = 0;   // lane w (<16) owns bitset word w
#pragma unroll
    for (int w = 0; w < 16; ++w) {
        int j = w * 64 + lane;
        bool v = (j < KTOP) ? (selSc[base + j] > 0.05f) : false;
        u64 mk = __ballot(v);
        if (lane == w) validW = mk;
    }
    __shared__ int keptIdx[DETS];
    int cnt = 0;
    const u64* rows = iouMask + (size_t)img * KTOP * 16;
    for (int i = 0; i < KTOP; ++i) {
        int w0 = i >> 6, b0 = i & 63;
        u64 rw = __shfl(removed, w0);
        u64 vw = __shfl(validW, w0);
        bool sup = (rw >> b0) & 1ULL;
        bool val = (vw >> b0) & 1ULL;
        if (val && !sup) {
            if (lane < 16) removed |= rows[(size_t)i * 16 + lane];
            if (lane == 0) keptIdx[cnt] = i;
            cnt++;
            if (cnt == DETS) break;
        }
    }
    __syncthreads();
    for (int r = lane; r < DETS; r += 64) {
        float b0 = 0.f, b1 = 0.f, b2 = 0.f, b3 = 0.f, sc = 0.f, lb = -1.0f, vd = 0.f;
        if (r < cnt) {
            int i = keptIdx[r];
            float4 bb = ((const float4*)selBox)[base + i];
            b0 = bb.x; b1 = bb.y; b2 = bb.z; b3 = bb.w;
            sc = selSc[base + i];
            lb = (float)(selCl[base + i] + 1);
            vd = 1.0f;
        }
        ((float4*)out)[(size_t)img * DETS + r] = make_float4(b0, b1, b2, b3);
        out[(size_t)B * 400 + (size_t)img * DETS + r] = sc;   // scores
        out[(size_t)B * 500 + (size_t)img * DETS + r] = lb;   // labels (as f32)
        out[(size_t)B * 600 + (size_t)img * DETS + r] = vd;   // valid (as f32)
    }
}

extern "C" void kernel_launch(void* const* d_in, const int* in_sizes, int n_in,
                              void* d_out, int out_size, void* d_ws, size_t ws_size,
                              hipStream_t stream)
{
    const float* logits = (const float*)d_in[0];
    const float* rel    = (const float*)d_in[1];
    const float* priors = (const float*)d_in[2];
    const float* ts     = (const float*)d_in[3];
    float* out = (float*)d_out;
    int P = in_sizes[2] / 4;
    int B = in_sizes[3] / 2;

    char* ws = (char*)d_ws;
    size_t o_bigcnt  = 0;                                        // padded counters
    size_t o_candcnt = o_bigcnt + (size_t)B * CNT_STRIDE * 4;
    size_t o_floor   = o_candcnt + (size_t)B * CNT_STRIDE * 4;
    size_t zero_bytes = o_floor;                                 // both counter arrays
    size_t o_cand    = (o_floor + (size_t)B * 4 + 255) & ~(size_t)255;
    size_t o_selboxD = o_cand + (size_t)B * CANDCAP * 8;
    size_t o_selbox  = o_selboxD + (size_t)B * 1024 * 32;
    size_t o_selsc   = o_selbox + (size_t)B * 1024 * 16;
    size_t o_selcl   = o_selsc + (size_t)B * 1024 * 4;
    size_t o_maxc    = o_selcl + (size_t)B * 1024 * 4;
    size_t o_iou     = (o_maxc + (size_t)B * 8 + 255) & ~(size_t)255;
    size_t o_big     = o_iou + (size_t)B * KTOP * 16 * 8;

    u32* bigCnt     = (u32*)(ws + o_bigcnt);
    u32* candCnt    = (u32*)(ws + o_candcnt);
    u32* floorKey   = (u32*)(ws + o_floor);
    u64* cand       = (u64*)(ws + o_cand);
    double* selBoxD = (double*)(ws + o_selboxD);
    float* selBox   = (float*)(ws + o_selbox);
    float* selSc    = (float*)(ws + o_selsc);
    int*   selCl    = (int*)(ws + o_selcl);
    double* maxc    = (double*)(ws + o_maxc);
    u64* iouMask    = (u64*)(ws + o_iou);
    u64* bigCand    = (u64*)(ws + o_big);

    hipMemsetAsync(ws, 0, zero_bytes, stream);

    dim3 g1((P + TPB - 1) / TPB, B);
    score_kernel<<<g1, TPB, 0, stream>>>(logits, rel, priors, ts, P, bigCand, bigCnt);
    floor_kernel<<<B, 1024, 0, stream>>>(bigCand, bigCnt, floorKey);
    compact_kernel<<<dim3(BIGCAP / 256, B), 256, 0, stream>>>(bigCand, bigCnt, floorKey,
                                                              cand, candCnt);
    sort_select_kernel<<<B, 1024, 0, stream>>>(cand, candCnt, rel, priors, ts, P,
                                               selBoxD, selBox, selSc, selCl, maxc);
    iou_kernel<<<dim3((KTOP + ROWTILE - 1) / ROWTILE, B), 256, 0, stream>>>(
        selBoxD, selCl, maxc, iouMask);
    nms_out_kernel<<<B, 64, 0, stream>>>(selBox, selSc, selCl, iouMask, out, B);
    (void)n_in; (void)out_size; (void)ws_size;
}

// Round 9
// 518.153 us; speedup vs baseline: 18.5479x; 1.1655x over previous
//
#include <hip/hip_runtime.h>
#include <stdint.h>

typedef unsigned int u32;
typedef unsigned long long u64;
typedef long long i64;

#define NCLS 81
#define KTOP 1000
#define DETS 100
#define CANDCAP 4096
#define BIGCAP 131072
#define ROWTILE 16
#define TPB 256
#define CH 27             // 81 = 3 chunks of 27; LDS tile 256*27*4 = 27.6 KB
#define CNT_STRIDE 32     // pad per-image counters to 128 B (atomic line isolation)
#define FBINS 4096

// ---------------------------------------------------------------------------
// Fast inline f64 exp: |x| <= ~40, rel err ~1e-15 (degree-12 Taylor + 2-part
// ln2 reduction). Avoids ocml lib-call.
// ---------------------------------------------------------------------------
__device__ __forceinline__ double fast_exp(double x)
{
    const double LOG2E = 1.4426950408889634074;
    const double LN2HI = 6.93147180369123816490e-01;
    const double LN2LO = 1.90821492927058770002e-10;
    double nf = rint(x * LOG2E);
    int n = (int)nf;
    double r = fma(-nf, LN2HI, x);
    r = fma(-nf, LN2LO, r);
    double p = 2.0876756987868099e-09;          // 1/12!
    p = fma(p, r, 2.5052108385441720e-08);
    p = fma(p, r, 2.7557319223985891e-07);
    p = fma(p, r, 2.7557319223985893e-06);
    p = fma(p, r, 2.4801587301587302e-05);
    p = fma(p, r, 1.9841269841269841e-04);
    p = fma(p, r, 1.3888888888888889e-03);
    p = fma(p, r, 8.3333333333333332e-03);
    p = fma(p, r, 4.1666666666666664e-02);
    p = fma(p, r, 1.6666666666666666e-01);
    p = fma(p, r, 5.0000000000000000e-01);
    p = fma(p, r, 1.0);
    p = fma(p, r, 1.0);
    i64 bits = ((i64)(n + 1023)) << 52;         // 2^n (n in [-40, 3] here)
    return p * __longlong_as_double(bits);
}

// ---------------------------------------------------------------------------
// Chunked score kernel: 3 staging phases of 27 classes (27.6 KB LDS) for the
// online-f64 softmax denominator, then 3 more for count+emit. 20 waves/CU
// (vs 6 at the 41.5 KB monolithic tile). Selection semantics preserved:
// f32-exact max, f64 exp/sum (online rescale, ~1e-15 rel), f64 threshold,
// per-chunk block scan + 1 line-isolated atomic, plain stores.
// ---------------------------------------------------------------------------
__global__ __launch_bounds__(TPB, 5)
void score_kernel(const float* __restrict__ logits, const float* __restrict__ rel,
                  const float* __restrict__ priors, const float* __restrict__ ts,
                  int P, u64* __restrict__ bigCand, u32* __restrict__ bigCnt)
{
    __shared__ float xs[TPB * CH];       // 27648 B
    __shared__ u32 wsum[4];
    __shared__ u32 s_base;
    int img = blockIdx.y;
    int p0 = blockIdx.x * TPB;
    int tid = threadIdx.x;
    int lane = tid & 63, wid = tid >> 6;
    int nrows = min(TPB, P - p0);
    const float* src = logits + ((size_t)img * P + p0) * NCLS;
    int p = p0 + tid;
    bool live = (tid < nrows);

    // ---- denominator: online f64 softmax over 3 class-chunks ----
    float m = -3.4e38f;
    double acc = 0.0;
    for (int c0 = 0; c0 < NCLS; c0 += CH) {
        __syncthreads();                 // previous chunk fully consumed
        int nflat = nrows * CH;
        for (int f = tid; f < nflat; f += TPB) {
            int r = f / CH, cc = f - r * CH;
            xs[r * CH + cc] = src[r * NCLS + c0 + cc];
        }
        __syncthreads();
        if (live) {
            const float* row = xs + tid * CH;
            float mc = row[0];
            for (int j = 1; j < CH; ++j) mc = fmaxf(mc, row[j]);   // exact max
            float mn = fmaxf(m, mc);
            if (c0 > 0) acc *= fast_exp((double)m - (double)mn);   // exp(0)==1.0 exact
            double mnd = (double)mn;
            for (int j = 0; j < CH; ++j)
                acc += fast_exp((double)row[j] - mnd);
            m = mn;
        }
    }
    double s = acc;
    double md = (double)m;
    float tf_lo = 3.4e38f;
    bool ok = false;
    if (live) {
        tf_lo = logf(0.05f * (float)s) - 3e-4f;   // conservative f32 prefilter

        // f64 size filter (unchanged semantics)
        const float* rp = rel + ((size_t)img * P + p) * 4;
        const float* pp = priors + (size_t)p * 4;
        double pw = pp[2], ph = pp[3];
        double cx = (double)pp[0] + (double)rp[0] * 0.1 * pw;
        double cy = (double)pp[1] + (double)rp[1] * 0.1 * ph;
        double bw = pw * fast_exp((double)rp[2] * 0.2);
        double bh = ph * fast_exp((double)rp[3] * 0.2);
        double sw = (double)ts[img * 2 + 1], sh = (double)ts[img * 2 + 0];
        double x1 = (cx - bw * 0.5) * sw, x2 = (cx + bw * 0.5) * sw;
        double y1 = (cy - bh * 0.5) * sh, y2 = (cy + bh * 0.5) * sh;
        ok = (x2 - x1 >= 0.01) && (y2 - y1 >= 0.01);
    }

    // ---- count + emit, per chunk (3 atomics/block, line-isolated) ----
    for (int c0 = 0; c0 < NCLS; c0 += CH) {
        __syncthreads();
        int nflat = nrows * CH;
        for (int f = tid; f < nflat; f += TPB) {
            int r = f / CH, cc = f - r * CH;
            xs[r * CH + cc] = src[r * NCLS + c0 + cc];
        }
        __syncthreads();
        const float* row = xs + tid * CH;
        int j0 = (c0 == 0) ? 1 : 0;                // skip background class 0
        u32 cnt = 0;
        if (ok) {
            for (int j = j0; j < CH; ++j) {
                float df = row[j] - m;
                if (df > tf_lo) {                  // rare (~0.8/prior/chunk)
                    double e = fast_exp((double)row[j] - md);
                    if (e / s > 0.05) cnt++;
                }
            }
        }
        // wave-level inclusive scan (no barriers), then tiny LDS combine
        u32 inc = cnt;
        for (int off = 1; off < 64; off <<= 1) {
            u32 v = __shfl_up(inc, off);
            if (lane >= off) inc += v;
        }
        if (lane == 63) wsum[wid] = inc;
        __syncthreads();
        if (tid == 0) {
            u32 tot = wsum[0] + wsum[1] + wsum[2] + wsum[3];
            s_base = tot ? atomicAdd(&bigCnt[(size_t)img * CNT_STRIDE], tot) : 0u;
        }
        __syncthreads();
        if (ok && cnt) {
            u32 wbase = 0;
            for (int w = 0; w < wid; ++w) wbase += wsum[w];
            u32 pos = s_base + wbase + inc - cnt;  // exclusive prefix
            for (int j = j0; j < CH; ++j) {
                float df = row[j] - m;
                if (df > tf_lo) {
                    double e = fast_exp((double)row[j] - md);
                    double sc = e / s;
                    if (sc > 0.05) {
                        u32 key = __float_as_uint((float)sc) ^ 0x80000000u;
                        if (pos < BIGCAP) {
                            u32 idx = (u32)p * 80u + (u32)(c0 + j - 1);
                            // sort key: (score desc, idx asc) == u64 desc
                            bigCand[(size_t)img * BIGCAP + pos] =
                                ((u64)key << 32) | (u64)(u32)(~idx);
                        }
                        pos++;
                    }
                }
            }
        }
    }
}

// ---------------------------------------------------------------------------
// One block per image: 16-bit floor key from bigCand via two LDS-hist passes
// (4096-bin on key[31:20], then 16-bin on key[19:16]).
// ---------------------------------------------------------------------------
__global__ __launch_bounds__(1024)
void floor_kernel(const u64* __restrict__ bigCand, const u32* __restrict__ bigCnt,
                  u32* __restrict__ floorKey)
{
    int img = blockIdx.x;
    int tid = threadIdx.x;
    __shared__ u32 h[FBINS];
    __shared__ u32 s_sel, s_run;
    u32 bc = bigCnt[(size_t)img * CNT_STRIDE];
    if (bc > (u32)BIGCAP) bc = BIGCAP;
    const u64* src = bigCand + (size_t)img * BIGCAP;

    for (int i = tid; i < FBINS; i += 1024) h[i] = 0;
    __syncthreads();
    for (u32 k = tid; k < bc; k += 1024)
        atomicAdd(&h[(u32)(src[k] >> 32) >> 20], 1u);
    __syncthreads();
    if (tid == 0) {
        u32 run = 0; int d = FBINS - 1;
        for (; d >= 0; --d) {
            if (run + h[d] >= KTOP) break;
            run += h[d];
        }
        s_sel = (u32)d;          // 0xFFFFFFFF if d == -1 (total < KTOP)
        s_run = run;
    }
    __syncthreads();
    u32 d12 = s_sel;
    if ((int)d12 < 0) { if (tid == 0) floorKey[img] = 0u; return; }
    u32 run0 = s_run;
    if (tid < 16) h[tid] = 0;
    __syncthreads();
    for (u32 k = tid; k < bc; k += 1024) {
        u32 key = (u32)(src[k] >> 32);
        if ((key >> 20) == d12) atomicAdd(&h[(key >> 16) & 0xF], 1u);
    }
    __syncthreads();
    if (tid == 0) {
        u32 run = run0;
        int b = 15;
        for (; b >= 0; --b) {
            run += h[b];
            if (run >= KTOP) break;
        }
        if (b < 0) b = 0;
        floorKey[img] = ((d12 << 4) | (u32)b) << 16;
    }
}

// Filter big candidate list down to key >= floorKey (wave-aggregated atomic).
__global__ __launch_bounds__(256)
void compact_kernel(const u64* __restrict__ big, const u32* __restrict__ bigCnt,
                    const u32* __restrict__ floorKey,
                    u64* __restrict__ cand, u32* __restrict__ candCnt)
{
    int img = blockIdx.y;
    int lane = threadIdx.x & 63;
    u32 bc = bigCnt[(size_t)img * CNT_STRIDE]; if (bc > (u32)BIGCAP) bc = BIGCAP;
    u32 k = blockIdx.x * 256 + threadIdx.x;
    u64 e = 0; bool pass = false;
    if (k < bc) {
        e = big[(size_t)img * BIGCAP + k];
        pass = ((u32)(e >> 32) >= floorKey[img]);
    }
    u64 mask = __ballot(pass);
    if (!mask) return;
    int leader = __ffsll((long long)mask) - 1;
    u32 basePos = 0;
    if (lane == leader)
        basePos = atomicAdd(&candCnt[(size_t)img * CNT_STRIDE], (u32)__popcll(mask));
    basePos = __shfl(basePos, leader);
    if (pass) {
        u32 pos = basePos + (u32)__popcll(mask & ((1ULL << lane) - 1ULL));
        if (pos < CANDCAP) cand[(size_t)img * CANDCAP + pos] = e;
    }
}

// Bitonic-sort candidates (desc), take top-1000, f64-decode their boxes,
// store f64 (for IoU) + f32 (for output), reduce maxc in f64.
__global__ __launch_bounds__(1024)
void sort_select_kernel(const u64* __restrict__ cand, const u32* __restrict__ candCnt,
                        const float* __restrict__ rel, const float* __restrict__ priors,
                        const float* __restrict__ ts, int P,
                        double* __restrict__ selBoxD, float* __restrict__ selBox,
                        float* __restrict__ selSc, int* __restrict__ selCl,
                        double* __restrict__ maxcArr)
{
    int img = blockIdx.x;
    int tid = threadIdx.x;
    __shared__ u64 s[CANDCAP];
    u32 n = candCnt[(size_t)img * CNT_STRIDE]; if (n > CANDCAP) n = CANDCAP;
    for (int k = tid; k < CANDCAP; k += 1024)
        s[k] = (k < (int)n) ? cand[(size_t)img * CANDCAP + k] : 0ULL;
    __syncthreads();
    for (u32 len = 2; len <= CANDCAP; len <<= 1) {
        for (u32 j = len >> 1; j > 0; j >>= 1) {
            for (int i = tid; i < CANDCAP; i += 1024) {
                u32 ixj = (u32)i ^ j;
                if (ixj > (u32)i) {
                    u64 a = s[i], b = s[ixj];
                    bool up = ((i & len) == 0);          // descending overall
                    if (up ? (a < b) : (a > b)) { s[i] = b; s[ixj] = a; }
                }
            }
            __syncthreads();
        }
    }
    double v = -1e300;
    if (tid < KTOP) {
        u64 e = s[tid];
        float score = -1.0f; int cls = 0;
        double b0 = 0, b1 = 0, b2 = 0, b3 = 0;
        if ((e >> 32) != 0ULL) {
            u32 key = (u32)(e >> 32);
            score = __uint_as_float(key ^ 0x80000000u);
            u32 idx = ~((u32)e);
            int p = (int)(idx / 80u), c0 = (int)(idx % 80u);
            cls = c0;
            const float* rp = rel + ((size_t)img * P + p) * 4;
            const float* pp = priors + (size_t)p * 4;
            double pw = pp[2], ph = pp[3];
            double cx = (double)pp[0] + (double)rp[0] * 0.1 * pw;
            double cy = (double)pp[1] + (double)rp[1] * 0.1 * ph;
            double bw = pw * fast_exp((double)rp[2] * 0.2);
            double bh = ph * fast_exp((double)rp[3] * 0.2);
            double sw = (double)ts[img * 2 + 1], sh = (double)ts[img * 2 + 0];
            b0 = (cx - bw * 0.5) * sw; b1 = (cy - bh * 0.5) * sh;
            b2 = (cx + bw * 0.5) * sw; b3 = (cy + bh * 0.5) * sh;
            v = fmax(fmax(b0, b1), fmax(b2, b3));   // valid -> box coords
        } else {
            v = 0.0;                                // invalid -> 0 (where(valid,b,0))
        }
        size_t o = (size_t)img * 1024 + tid;
        selSc[o] = score; selCl[o] = cls;
        selBoxD[o * 4 + 0] = b0; selBoxD[o * 4 + 1] = b1;
        selBoxD[o * 4 + 2] = b2; selBoxD[o * 4 + 3] = b3;
        ((float4*)selBox)[o] = make_float4((float)b0, (float)b1, (float)b2, (float)b3);
    }
    __shared__ double red[1024];
    red[tid] = v;
    __syncthreads();
    for (int off = 512; off > 0; off >>= 1) {
        if (tid < off) red[tid] = fmax(red[tid], red[tid + off]);
        __syncthreads();
    }
    if (tid == 0) maxcArr[img] = red[0];
}

// 16 rows per block, 1000 boxes staged in LDS; f64 IoU on class-offset boxes
// -> 16-word bitmask row per i. Division replaced by multiply compare
// (inter/(u+eps) > t  <=>  inter > t*(u+eps), u+eps > 0; flip window ~1e-16).
__global__ __launch_bounds__(256)
void iou_kernel(const double* __restrict__ selBoxD, const int* __restrict__ selCl,
                const double* __restrict__ maxcArr, u64* __restrict__ iouMask)
{
    int img = blockIdx.y;
    int i0 = blockIdx.x * ROWTILE;
    int tid = threadIdx.x, wave = tid >> 6, lane = tid & 63;
    __shared__ double sb[KTOP][5];   // pad stride 40B
    __shared__ int scls[KTOP];
    size_t base = (size_t)img * 1024;
    for (int j = tid; j < KTOP; j += 256) {
        sb[j][0] = selBoxD[(base + j) * 4 + 0];
        sb[j][1] = selBoxD[(base + j) * 4 + 1];
        sb[j][2] = selBoxD[(base + j) * 4 + 2];
        sb[j][3] = selBoxD[(base + j) * 4 + 3];
        scls[j] = selCl[base + j];
    }
    __syncthreads();
    double maxc1 = maxcArr[img] + 1.0;
    for (int r = 0; r < 4; ++r) {
        int i = i0 + wave * 4 + r;           // uniform across the wave
        if (i >= KTOP) continue;
        double offA = (double)scls[i] * maxc1;
        double a0 = sb[i][0] + offA, a1 = sb[i][1] + offA;
        double a2 = sb[i][2] + offA, a3 = sb[i][3] + offA;
        double areaA = (a2 - a0) * (a3 - a1);
        for (int ch = 0; ch < 16; ++ch) {
            int j = ch * 64 + lane;
            bool pred = false;
            if (j < KTOP) {
                double offB = (double)scls[j] * maxc1;
                double b0 = sb[j][0] + offB, b1 = sb[j][1] + offB;
                double b2 = sb[j][2] + offB, b3 = sb[j][3] + offB;
                double areaB = (b2 - b0) * (b3 - b1);
                double ltx = fmax(a0, b0), lty = fmax(a1, b1);
                double rbx = fmin(a2, b2), rby = fmin(a3, b3);
                double wx = fmax(rbx - ltx, 0.0), wy = fmax(rby - lty, 0.0);
                double inter = wx * wy;
                pred = inter > 0.45 * (((areaA + areaB) - inter) + 1e-12);
            }
            u64 bal = __ballot(pred);
            if (lane == 0) iouMask[((size_t)img * KTOP + i) * 16 + ch] = bal;
        }
    }
}

// Single-wave sequential greedy NMS + final top-100 write-out.
__global__ __launch_bounds__(64)
void nms_out_kernel(const float* __restrict__ selBox, const float* __restrict__ selSc,
                    const int* __restrict__ selCl, const u64* __restrict__ iouMask,
                    float* __restrict__ out, int B)
{
    int img = blockIdx.x;
    int lane = threadIdx.x;
    size_t base = (size_t)img * 1024;
    u64 validW = 0, removed = 0;   // lane w (<16) owns bitset word w
#pragma unroll
    for (int w = 0; w < 16; ++w) {
        int j = w * 64 + lane;
        bool v = (j < KTOP) ? (selSc[base + j] > 0.05f) : false;
        u64 mk = __ballot(v);
        if (lane == w) validW = mk;
    }
    __shared__ int keptIdx[DETS];
    int cnt = 0;
    const u64* rows = iouMask + (size_t)img * KTOP * 16;
    for (int i = 0; i < KTOP; ++i) {
        int w0 = i >> 6, b0 = i & 63;
        u64 rw = __shfl(removed, w0);
        u64 vw = __shfl(validW, w0);
        bool sup = (rw >> b0) & 1ULL;
        bool val = (vw >> b0) & 1ULL;
        if (val && !sup) {
            if (lane < 16) removed |= rows[(size_t)i * 16 + lane];
            if (lane == 0) keptIdx[cnt] = i;
            cnt++;
            if (cnt == DETS) break;
        }
    }
    __syncthreads();
    for (int r = lane; r < DETS; r += 64) {
        float b0 = 0.f, b1 = 0.f, b2 = 0.f, b3 = 0.f, sc = 0.f, lb = -1.0f, vd = 0.f;
        if (r < cnt) {
            int i = keptIdx[r];
            float4 bb = ((const float4*)selBox)[base + i];
            b0 = bb.x; b1 = bb.y; b2 = bb.z; b3 = bb.w;
            sc = selSc[base + i];
            lb = (float)(selCl[base + i] + 1);
            vd = 1.0f;
        }
        ((float4*)out)[(size_t)img * DETS + r] = make_float4(b0, b1, b2, b3);
        out[(size_t)B * 400 + (size_t)img * DETS + r] = sc;   // scores
        out[(size_t)B * 500 + (size_t)img * DETS + r] = lb;   // labels (as f32)
        out[(size_t)B * 600 + (size_t)img * DETS + r] = vd;   // valid (as f32)
    }
}

extern "C" void kernel_launch(void* const* d_in, const int* in_sizes, int n_in,
                              void* d_out, int out_size, void* d_ws, size_t ws_size,
                              hipStream_t stream)
{
    const float* logits = (const float*)d_in[0];
    const float* rel    = (const float*)d_in[1];
    const float* priors = (const float*)d_in[2];
    const float* ts     = (const float*)d_in[3];
    float* out = (float*)d_out;
    int P = in_sizes[2] / 4;
    int B = in_sizes[3] / 2;

    char* ws = (char*)d_ws;
    size_t o_bigcnt  = 0;                                        // padded counters
    size_t o_candcnt = o_bigcnt + (size_t)B * CNT_STRIDE * 4;
    size_t o_floor   = o_candcnt + (size_t)B * CNT_STRIDE * 4;
    size_t zero_bytes = o_floor;                                 // both counter arrays
    size_t o_cand    = (o_floor + (size_t)B * 4 + 255) & ~(size_t)255;
    size_t o_selboxD = o_cand + (size_t)B * CANDCAP * 8;
    size_t o_selbox  = o_selboxD + (size_t)B * 1024 * 32;
    size_t o_selsc   = o_selbox + (size_t)B * 1024 * 16;
    size_t o_selcl   = o_selsc + (size_t)B * 1024 * 4;
    size_t o_maxc    = o_selcl + (size_t)B * 1024 * 4;
    size_t o_iou     = (o_maxc + (size_t)B * 8 + 255) & ~(size_t)255;
    size_t o_big     = o_iou + (size_t)B * KTOP * 16 * 8;

    u32* bigCnt     = (u32*)(ws + o_bigcnt);
    u32* candCnt    = (u32*)(ws + o_candcnt);
    u32* floorKey   = (u32*)(ws + o_floor);
    u64* cand       = (u64*)(ws + o_cand);
    double* selBoxD = (double*)(ws + o_selboxD);
    float* selBox   = (float*)(ws + o_selbox);
    float* selSc    = (float*)(ws + o_selsc);
    int*   selCl    = (int*)(ws + o_selcl);
    double* maxc    = (double*)(ws + o_maxc);
    u64* iouMask    = (u64*)(ws + o_iou);
    u64* bigCand    = (u64*)(ws + o_big);

    hipMemsetAsync(ws, 0, zero_bytes, stream);

    dim3 g1((P + TPB - 1) / TPB, B);
    score_kernel<<<g1, TPB, 0, stream>>>(logits, rel, priors, ts, P, bigCand, bigCnt);
    floor_kernel<<<B, 1024, 0, stream>>>(bigCand, bigCnt, floorKey);
    compact_kernel<<<dim3(BIGCAP / 256, B), 256, 0, stream>>>(bigCand, bigCnt, floorKey,
                                                              cand, candCnt);
    sort_select_kernel<<<B, 1024, 0, stream>>>(cand, candCnt, rel, priors, ts, P,
                                               selBoxD, selBox, selSc, selCl, maxc);
    iou_kernel<<<dim3((KTOP + ROWTILE - 1) / ROWTILE, B), 256, 0, stream>>>(
        selBoxD, selCl, maxc, iouMask);
    nms_out_kernel<<<B, 64, 0, stream>>>(selBox, selSc, selCl, iouMask, out, B);
    (void)n_in; (void)out_size; (void)ws_size;
}